// Round 2
// baseline (158.685 us; speedup 1.0000x reference)
//
#include <hip/hip_runtime.h>
#include <hip/hip_bf16.h>

// Problem constants (match reference)
constexpr int kT    = 3;
constexpr int kB    = 8;
constexpr int kN    = 512;
constexpr int kFIN  = 256;
constexpr int kFOUT = 128;
constexpr int kNE   = 10;          // emb has kNE+1 rows
constexpr float kALPHA = 0.2f;
constexpr float kNEG   = -9e15f;

// ---------------------------------------------------------------------------
// Kernel 1: typed projection
//   h[row,o] = sum_t mask[t,row] * (node_rep[row,:] @ W[t,:,o] + b[t,o])
//   s1[row] = h[row,:]·a1 ;  s2[row] = h[row,:]·a2
// 16 rows per block, 256 threads (thread = (row-half, out-feature)).
// ---------------------------------------------------------------------------
constexpr int ROWS1 = 16;

__global__ __launch_bounds__(256) void proj_kernel(
    const float* __restrict__ node_rep,  // (B*N, FIN)
    const float* __restrict__ mask,      // (T, B*N)
    const float* __restrict__ W,         // (T, FIN, FOUT)
    const float* __restrict__ bias,      // (T, FOUT)
    const float* __restrict__ a1,        // (FOUT)
    const float* __restrict__ a2,        // (FOUT)
    float* __restrict__ h,               // (B*N, FOUT)
    float* __restrict__ s1,              // (B*N)
    float* __restrict__ s2)              // (B*N)
{
    __shared__ float xs[ROWS1][kFIN];    // 16 KB
    __shared__ float hs[ROWS1][kFOUT];   //  8 KB

    const int tid  = threadIdx.x;
    const int row0 = blockIdx.x * ROWS1;

    // stage node_rep rows (coalesced)
    for (int idx = tid; idx < ROWS1 * kFIN; idx += 256) {
        int r = idx >> 8;          // / kFIN
        int i = idx & (kFIN - 1);
        xs[r][i] = node_rep[(row0 + r) * kFIN + i];
    }
    __syncthreads();

    const int o  = tid & (kFOUT - 1);   // output feature
    const int rh = tid >> 7;            // 0/1 -> rows rh*8 .. rh*8+7

    float acc0[8], acc1[8], acc2[8];
    #pragma unroll
    for (int r = 0; r < 8; ++r) { acc0[r] = 0.f; acc1[r] = 0.f; acc2[r] = 0.f; }

    for (int i = 0; i < kFIN; ++i) {
        float w0 = W[(0 * kFIN + i) * kFOUT + o];
        float w1 = W[(1 * kFIN + i) * kFOUT + o];
        float w2 = W[(2 * kFIN + i) * kFOUT + o];
        #pragma unroll
        for (int r = 0; r < 8; ++r) {
            float x = xs[rh * 8 + r][i];
            acc0[r] = fmaf(w0, x, acc0[r]);
            acc1[r] = fmaf(w1, x, acc1[r]);
            acc2[r] = fmaf(w2, x, acc2[r]);
        }
    }

    const float b0 = bias[0 * kFOUT + o];
    const float b1 = bias[1 * kFOUT + o];
    const float b2 = bias[2 * kFOUT + o];
    #pragma unroll
    for (int r = 0; r < 8; ++r) {
        int row = row0 + rh * 8 + r;
        float m0 = mask[0 * kB * kN + row];
        float m1 = mask[1 * kB * kN + row];
        float m2 = mask[2 * kB * kN + row];
        float hv = m0 * (acc0[r] + b0) + m1 * (acc1[r] + b1) + m2 * (acc2[r] + b2);
        h[row * kFOUT + o] = hv;
        hs[rh * 8 + r][o]  = hv;
    }
    __syncthreads();

    // s1/s2 reductions: wave w handles rows w*4 .. w*4+3
    const int wave = tid >> 6;
    const int lane = tid & 63;
    for (int rr = 0; rr < 4; ++rr) {
        int r = wave * 4 + rr;
        float v0 = hs[r][lane];
        float v1 = hs[r][lane + 64];
        float p1 = v0 * a1[lane] + v1 * a1[lane + 64];
        float p2 = v0 * a2[lane] + v1 * a2[lane + 64];
        #pragma unroll
        for (int off = 32; off; off >>= 1) {
            p1 += __shfl_down(p1, off);
            p2 += __shfl_down(p2, off);
        }
        if (lane == 0) {
            s1[row0 + r] = p1;
            s2[row0 + r] = p2;
        }
    }
}

// ---------------------------------------------------------------------------
// Kernel 2: scores + softmax + weighted sum + ELU
//   s[i,j] = lrelu(s1[i] + s2[j] + emb_a2[adj[i,j]] + a_b); mask; softmax
//   out[i,f] = elu( sum_j attn[i,j] * (h[j,f] + emb[adj[i,j],f]) )
// 8 i-rows per block, 256 threads.
// ---------------------------------------------------------------------------
constexpr int TI = 8;

__global__ __launch_bounds__(256) void attn_kernel(
    const int*   __restrict__ adj,   // (B, N, N)
    const float* __restrict__ emb,   // (NE+1, FOUT)
    const float* __restrict__ a2,    // (FOUT)
    const float* __restrict__ a_b,   // scalar
    const float* __restrict__ h,     // (B*N, FOUT)
    const float* __restrict__ s1,    // (B*N)
    const float* __restrict__ s2,    // (B*N)
    float* __restrict__ out)         // (B*N, FOUT)
{
    __shared__ float embs[(kNE + 1) * kFOUT];  // 5.5 KB
    __shared__ float emb_a2[kNE + 1];
    __shared__ float sc[TI][kN];               // 16 KB (scores -> attn)
    __shared__ int   adjs[TI][kN];             // 16 KB

    const int tid = threadIdx.x;
    const int b   = blockIdx.x / (kN / TI);
    const int i0  = (blockIdx.x % (kN / TI)) * TI;

    // stage emb
    for (int idx = tid; idx < (kNE + 1) * kFOUT; idx += 256)
        embs[idx] = emb[idx];
    __syncthreads();

    // emb·a2 table (tiny)
    if (tid < kNE + 1) {
        float acc = 0.f;
        for (int f = 0; f < kFOUT; ++f) acc += embs[tid * kFOUT + f] * a2[f];
        emb_a2[tid] = acc;
    }
    // stage adj rows (coalesced)
    for (int idx = tid; idx < TI * kN; idx += 256) {
        int r = idx >> 9;          // / kN
        int j = idx & (kN - 1);
        adjs[r][j] = adj[(b * kN + i0 + r) * kN + j];
    }
    __syncthreads();

    const float ab = a_b[0];

    // scores
    for (int idx = tid; idx < TI * kN; idx += 256) {
        int r = idx >> 9;
        int j = idx & (kN - 1);
        int a = adjs[r][j];
        float s = s1[b * kN + i0 + r] + s2[b * kN + j] + emb_a2[a] + ab;
        s = (s > 0.f) ? s : kALPHA * s;
        sc[r][j] = (a > 0) ? s : kNEG;
    }
    __syncthreads();

    // per-row softmax: wave w handles rows 2w, 2w+1
    const int wave = tid >> 6;
    const int lane = tid & 63;
    for (int rr = 0; rr < 2; ++rr) {
        int r = wave * 2 + rr;
        float m = -3.402823466e38f;
        #pragma unroll
        for (int k = 0; k < 8; ++k) m = fmaxf(m, sc[r][lane + k * 64]);
        #pragma unroll
        for (int off = 32; off; off >>= 1) m = fmaxf(m, __shfl_down(m, off));
        m = __shfl(m, 0);
        float e[8];
        float sum = 0.f;
        #pragma unroll
        for (int k = 0; k < 8; ++k) {
            e[k] = __expf(sc[r][lane + k * 64] - m);
            sum += e[k];
        }
        #pragma unroll
        for (int off = 32; off; off >>= 1) sum += __shfl_down(sum, off);
        sum = __shfl(sum, 0);
        float inv = 1.0f / sum;
        #pragma unroll
        for (int k = 0; k < 8; ++k) sc[r][lane + k * 64] = e[k] * inv;
    }
    __syncthreads();

    // weighted sum: thread = (row-half, feature)
    const int f  = tid & (kFOUT - 1);
    const int rh = tid >> 7;            // rows rh*4 .. rh*4+3
    float acc[4] = {0.f, 0.f, 0.f, 0.f};
    const float* hb = h + (size_t)b * kN * kFOUT;
    for (int j = 0; j < kN; ++j) {
        float hv = hb[j * kFOUT + f];
        #pragma unroll
        for (int r = 0; r < 4; ++r) {
            int rr = rh * 4 + r;
            int a  = adjs[rr][j];
            acc[r] = fmaf(sc[rr][j], hv + embs[a * kFOUT + f], acc[r]);
        }
    }
    #pragma unroll
    for (int r = 0; r < 4; ++r) {
        int row = i0 + rh * 4 + r;
        float v = acc[r];
        v = (v > 0.f) ? v : expm1f(v);   // ELU (alpha=1)
        out[((size_t)b * kN + row) * kFOUT + f] = v;
    }
}

// ---------------------------------------------------------------------------
extern "C" void kernel_launch(void* const* d_in, const int* in_sizes, int n_in,
                              void* d_out, int out_size, void* d_ws, size_t ws_size,
                              hipStream_t stream) {
    const float* node_rep = (const float*)d_in[0];
    const float* mask     = (const float*)d_in[1];
    const int*   adj      = (const int*)  d_in[2];
    const float* W        = (const float*)d_in[3];
    const float* bias     = (const float*)d_in[4];
    const float* a1       = (const float*)d_in[5];
    const float* a2       = (const float*)d_in[6];
    const float* a_b      = (const float*)d_in[7];
    const float* emb      = (const float*)d_in[8];
    float* out = (float*)d_out;

    float* ws = (float*)d_ws;
    float* h  = ws;                          // B*N*FOUT
    float* s1 = h + (size_t)kB * kN * kFOUT; // B*N
    float* s2 = s1 + kB * kN;                // B*N

    proj_kernel<<<(kB * kN) / ROWS1, 256, 0, stream>>>(
        node_rep, mask, W, bias, a1, a2, h, s1, s2);
    attn_kernel<<<kB * (kN / TI), 256, 0, stream>>>(
        adj, emb, a2, a_b, h, s1, s2, out);
}